// Round 4
// baseline (1835.441 us; speedup 1.0000x reference)
//
#include <hip/hip_runtime.h>
#include <stdint.h>

typedef __bf16 bf16;
typedef __bf16 bf16x4 __attribute__((ext_vector_type(4)));
typedef __bf16 bf16x8 __attribute__((ext_vector_type(8)));
typedef float f32x4 __attribute__((ext_vector_type(4)));

#define NB_REC 256   // 32 batches x 8 slices; 1 block/CU, groups independent

__device__ __forceinline__ float fast_tanh(float x) {
  x = fminf(fmaxf(x, -15.f), 15.f);
  float u = __expf(2.f * x);
  return (u - 1.f) / (u + 1.f);
}
__device__ __forceinline__ float fast_sigmoid(float x) {
  return 1.f / (1.f + __expf(-x));
}
__device__ __forceinline__ float bflo(unsigned u) {
  union { unsigned x; float f; } c; c.x = u << 16; return c.f;
}
__device__ __forceinline__ float bfhi(unsigned u) {
  union { unsigned x; float f; } c; c.x = u & 0xffff0000u; return c.f;
}

// ---------------- prep kernels ----------------
__global__ __launch_bounds__(256) void f2bf_k(const float* __restrict__ s,
                                              bf16* __restrict__ d, long n) {
  long i = ((long)blockIdx.x * 256 + threadIdx.x) * 4;
  if (i >= n) return;
  float4 v = *(const float4*)(s + i);
  bf16x4 o = {(bf16)v.x, (bf16)v.y, (bf16)v.z, (bf16)v.w};
  *(bf16x4*)(d + i) = o;
}

// split W_ih [1536,1024] into x-half [1536,512] and context-half [1536,512] (bf16)
__global__ __launch_bounds__(256) void split_wih_k(const float* __restrict__ W,
                                                   bf16* __restrict__ X,
                                                   bf16* __restrict__ Cc) {
  long i = ((long)blockIdx.x * 256 + threadIdx.x) * 4;  // over 1536*512
  if (i >= (long)1536 * 512) return;
  long j = i >> 9, k = i & 511;
  float4 a = *(const float4*)(W + j * 1024 + k);
  float4 b = *(const float4*)(W + j * 1024 + 512 + k);
  bf16x4 oa = {(bf16)a.x, (bf16)a.y, (bf16)a.z, (bf16)a.w};
  bf16x4 ob = {(bf16)b.x, (bf16)b.y, (bf16)b.z, (bf16)b.w};
  *(bf16x4*)(X + i) = oa;
  *(bf16x4*)(Cc + i) = ob;
}

// xemb[m = b*64+t, :] = bf16(emb[tok(b,t)]), tok = t==0 ? SOS(0) : target[b,t-1]
__global__ __launch_bounds__(256) void embed_k(const int* __restrict__ tgt,
                                               const float* __restrict__ emb,
                                               bf16* __restrict__ xe) {
  long i = ((long)blockIdx.x * 256 + threadIdx.x) * 4;  // over 2048*512
  if (i >= (long)2048 * 512) return;
  long m = i >> 9, k = i & 511;
  int b = (int)(m >> 6), t = (int)(m & 63);
  int tok = (t == 0) ? 0 : tgt[b * 64 + t - 1];
  float4 v = *(const float4*)(emb + (long)tok * 512 + k);
  bf16x4 o = {(bf16)v.x, (bf16)v.y, (bf16)v.z, (bf16)v.w};
  *(bf16x4*)(xe + i) = o;
}

// kpT[b][k][s] = kp[b*64+s][k]   (for coalesced lane=s reads in scores)
__global__ __launch_bounds__(256) void kpt_k(const float* __restrict__ kp,
                                             float* __restrict__ kpT) {
  long i = (long)blockIdx.x * 256 + threadIdx.x;  // over 32*512*64 = 1048576
  if (i >= (long)32 * 512 * 64) return;
  int b = (int)(i >> 15);
  int r = (int)(i & 32767);
  int k = r >> 6, s = r & 63;
  kpT[i] = kp[((long)b * 64 + s) * 512 + k];
}

// ---------------- bf16 MFMA GEMM:  C[2048,N] = A[2048,512] * B[N,512]^T (+bias[n]) ----------------
__global__ __launch_bounds__(256) void gemm_bt(const bf16* __restrict__ A,
                                               const bf16* __restrict__ Bm,
                                               const float* __restrict__ bias,
                                               float* __restrict__ C, int N) {
  __shared__ bf16 As[128 * 32];
  __shared__ bf16 Bs[128 * 32];
  const int tid = threadIdx.x;
  const int bx = blockIdx.x;
  const int bm = bx & 15;       // M/128 = 16
  const int bn = bx >> 4;
  const int lane = tid & 63;
  const int w = tid >> 6;
  const int l16 = lane & 15, q4 = lane >> 4;
  const int wm = (w & 1) * 64, wn = (w >> 1) * 64;
  const long m0 = (long)bm * 128;
  const long n0 = (long)bn * 128;
  const int r0 = tid >> 2;            // 0..63
  const int kp8 = (tid & 3) * 8;      // k-part within 32 (element units)

  f32x4 acc[4][4] = {};
  for (int kk = 0; kk < 512; kk += 32) {
    __syncthreads();
    {
      bf16x8 va0 = *(const bf16x8*)(A + (m0 + r0) * 512 + kk + kp8);
      bf16x8 va1 = *(const bf16x8*)(A + (m0 + 64 + r0) * 512 + kk + kp8);
      bf16x8 vb0 = *(const bf16x8*)(Bm + (n0 + r0) * 512 + kk + kp8);
      bf16x8 vb1 = *(const bf16x8*)(Bm + (n0 + 64 + r0) * 512 + kk + kp8);
      *(bf16x8*)&As[r0 * 32 + kp8] = va0;
      *(bf16x8*)&As[(64 + r0) * 32 + kp8] = va1;
      *(bf16x8*)&Bs[r0 * 32 + kp8] = vb0;
      *(bf16x8*)&Bs[(64 + r0) * 32 + kp8] = vb1;
    }
    __syncthreads();
    bf16x8 af[4], bfr[4];
#pragma unroll
    for (int i = 0; i < 4; ++i)
      af[i] = *(const bf16x8*)&As[(wm + i * 16 + l16) * 32 + q4 * 8];
#pragma unroll
    for (int j = 0; j < 4; ++j)
      bfr[j] = *(const bf16x8*)&Bs[(wn + j * 16 + l16) * 32 + q4 * 8];
#pragma unroll
    for (int i = 0; i < 4; ++i)
#pragma unroll
      for (int j = 0; j < 4; ++j)
        acc[i][j] = __builtin_amdgcn_mfma_f32_16x16x32_bf16(af[i], bfr[j], acc[i][j], 0, 0, 0);
  }
#pragma unroll
  for (int i = 0; i < 4; ++i) {
    const long rbase = m0 + wm + i * 16 + q4 * 4;
#pragma unroll
    for (int j = 0; j < 4; ++j) {
      const long col = n0 + wn + j * 16 + l16;
      const float bv = bias ? bias[col] : 0.f;
      f32x4 a = acc[i][j];
      C[(rbase + 0) * N + col] = a[0] + bv;
      C[(rbase + 1) * N + col] = a[1] + bv;
      C[(rbase + 2) * N + col] = a[2] + bv;
      C[(rbase + 3) * N + col] = a[3] + bv;
    }
  }
}

// ---------------- per-batch 8-block sync (no global barrier!) ----------------
// bar[b*32]: monotone arrival counter for group b (one 128B line per group).
// Arrival's s_waitcnt(0) drains this block's coherent loads AND stores, so
// peers' post-sync accesses are ordered (same reasoning as the round-0..2 gbar).
__device__ __forceinline__ void gsync(unsigned* bar, int b, unsigned target) {
  __syncthreads();
  if (threadIdx.x == 0) {
    __builtin_amdgcn_s_waitcnt(0);
    __atomic_signal_fence(__ATOMIC_SEQ_CST);
    __hip_atomic_fetch_add(&bar[b * 32], 1u, __ATOMIC_RELAXED, __HIP_MEMORY_SCOPE_AGENT);
    while (__hip_atomic_load(&bar[b * 32], __ATOMIC_RELAXED, __HIP_MEMORY_SCOPE_AGENT) <
           target)
      __builtin_amdgcn_s_sleep(1);
    __atomic_signal_fence(__ATOMIC_SEQ_CST);
  }
  __syncthreads();
}

__device__ __forceinline__ float coh_load_f32(const float* p) {
  return __hip_atomic_load(p, __ATOMIC_RELAXED, __HIP_MEMORY_SCOPE_AGENT);
}
__device__ __forceinline__ unsigned coh_load_u32(const unsigned* p) {
  return __hip_atomic_load(p, __ATOMIC_RELAXED, __HIP_MEMORY_SCOPE_AGENT);
}

// ---------------- persistent recurrence kernel (batch-local groups) ----------------
// Block (b = g&31, p = g>>5) owns h-slice j in [64p,64p+64).
// Weights resident in VGPRs: 1 row/thread, 512 bf16 = 64 uint4.
//   tid<64   : q-row  k = 64p+tid         (Wa row k,   bias ba[k])
//   tid>=64  : gh-row n = gate*512+64p+jj (Whh row n,  bias bhh[n]); u=tid-64,
//              gate=u>>6, jj=u&63
// Per step: reg-matvec q+gh -> partial scores (own k-slice) -> publish ps[64]
// -> [sync] -> sum 8, softmax, ctx from LDS ep, gates -> publish h-slice
// -> [sync] -> pull full h.
// h exchange: hx = [32][256] u32 (2 bf16 per u32; 512 bf16 per batch).
__global__ __launch_bounds__(256, 1) void recurrence_k(
    const bf16* __restrict__ Wc,      // [2048,512] = [Wa;W_hh] bf16
    const float* __restrict__ ba,     // [512]
    const float* __restrict__ bhh,    // [1536]
    const float* __restrict__ ehid,   // [32,512] h0 fp32
    unsigned* __restrict__ hx,        // [32*256] packed bf16 pairs (coherent)
    float* __restrict__ psx,          // [32*8*64] partial scores (coherent)
    bf16* __restrict__ histb,         // [2048,512] ordinary (next-kernel GEMM)
    const float* __restrict__ kpT,    // [32,512,64]
    const float* __restrict__ va,     // [512]
    const float* __restrict__ gix,    // [2048,1536]
    const float* __restrict__ ep,     // [2048,1536]
    float* __restrict__ outhT,        // [32,512]
    float* __restrict__ outattn,      // [2048,64]
    unsigned* __restrict__ bar) {
  const int g = blockIdx.x;
  const int tid = threadIdx.x;
  const int b = g & 31;
  const int p = g >> 5;
  __shared__ float kp_s[64 * 64];     // 16 KB: kpT[b][64p..64p+64)][s]
  __shared__ float ep_s[64 * 192];    // 48 KB: ep[b*64+s][cols of this block]
  __shared__ __align__(16) float h_s[512];
  __shared__ float q_s[64], gh_s[192], gi_s[192], part_s[256], w_s[64];
  __shared__ float va_s[64], h_loc[64];

  // ---- resident weights: 1 row/thread, 64 uint4 = 256 VGPRs (static idx) ----
  uint4 wv4[64];
  float mybias;
  {
    long myrow;
    if (tid < 64) {
      myrow = p * 64 + tid;                 // Wa row
      mybias = ba[myrow];
    } else {
      const int u = tid - 64;
      const int n = (u >> 6) * 512 + p * 64 + (u & 63);
      myrow = 512 + n;                      // Whh row
      mybias = bhh[n];
    }
    const uint4* wrow = (const uint4*)(Wc + myrow * 512);
#pragma unroll
    for (int i = 0; i < 64; ++i) wv4[i] = wrow[i];
  }

  // ---- one-time LDS staging (step-invariant) ----
  {
    const float* kpb = kpT + ((long)b * 512 + p * 64) * 64;  // 4096 contiguous
    for (int i = tid; i < 4096; i += 256) kp_s[i] = kpb[i];
    for (int s = 0; s < 64; ++s)
      if (tid < 192)
        ep_s[s * 192 + tid] =
            ep[(long)(b * 64 + s) * 1536 + (tid >> 6) * 512 + p * 64 + (tid & 63)];
    if (tid < 64) {
      va_s[tid] = va[p * 64 + tid];
      h_loc[tid] = ehid[b * 512 + p * 64 + tid];  // exact f32 state (own slice)
    }
    // t=0: full h0, bf16-rounded (matches weight-precision path)
    h_s[tid] = (float)(bf16)ehid[b * 512 + tid];
    h_s[256 + tid] = (float)(bf16)ehid[b * 512 + 256 + tid];
  }
  __syncthreads();

  const int wv_ = tid >> 6, ln = tid & 63;
  unsigned snc = 0;

  for (int t = 0; t < 64; ++t) {
    // prefetch this step's gix value (consumed after syncB)
    float gval = 0.f;
    if (tid < 192)
      gval = gix[(long)(b * 64 + t) * 1536 + (tid >> 6) * 512 + p * 64 + (tid & 63)];

    // ---- X1: register matvec: q-slice (tid<64) / gh-slice (tid>=64) ----
    {
      float acc = mybias;
#pragma unroll
      for (int i = 0; i < 64; ++i) {
        f32x4 h0 = *(const f32x4*)&h_s[i * 8];
        f32x4 h1 = *(const f32x4*)&h_s[i * 8 + 4];
        acc = fmaf(bflo(wv4[i].x), h0[0], acc);
        acc = fmaf(bfhi(wv4[i].x), h0[1], acc);
        acc = fmaf(bflo(wv4[i].y), h0[2], acc);
        acc = fmaf(bfhi(wv4[i].y), h0[3], acc);
        acc = fmaf(bflo(wv4[i].z), h1[0], acc);
        acc = fmaf(bfhi(wv4[i].z), h1[1], acc);
        acc = fmaf(bflo(wv4[i].w), h1[2], acc);
        acc = fmaf(bfhi(wv4[i].w), h1[3], acc);
      }
      if (tid < 64) q_s[tid] = acc;
      else gh_s[tid - 64] = acc;
    }
    __syncthreads();

    // ---- X2: partial scores over own k-slice. wave wv: k in [16wv,16wv+16), lane=s ----
    {
      float pacc = 0.f;
#pragma unroll
      for (int k2 = 0; k2 < 16; ++k2) {
        const int kl = wv_ * 16 + k2;
        pacc += va_s[kl] * fast_tanh(q_s[kl] + kp_s[kl * 64 + ln]);
      }
      part_s[tid] = pacc;
    }
    __syncthreads();
    if (tid < 64) {  // 4-wave local reduce -> publish my partial score
      float ps = part_s[tid] + part_s[64 + tid] + part_s[128 + tid] + part_s[192 + tid];
      __hip_atomic_store(&psx[(b * 8 + p) * 64 + tid], ps, __ATOMIC_RELAXED,
                         __HIP_MEMORY_SCOPE_AGENT);
    }
    gsync(bar, b, 8u * (++snc));   // syncB: all 8 partials published

    // ---- X3: sum partials -> softmax (replicated in all 8 blocks) ----
    if (tid < 64) {
      float sc = 0.f;
#pragma unroll
      for (int pp = 0; pp < 8; ++pp)
        sc += coh_load_f32(&psx[(b * 8 + pp) * 64 + tid]);
      float e = __expf(sc);   // bounded scores; no max-shift needed
      float sum = e;
#pragma unroll
      for (int d = 1; d < 64; d <<= 1) sum += __shfl_xor(sum, d);
      float wvx = e / sum;
      w_s[tid] = wvx;
      if (p == 0) outattn[(long)(b * 64 + t) * 64 + tid] = wvx;
    }
    __syncthreads();

    // ---- X4: gi slice = sum_s w_s * ep_s[s][col] + gix (prefetched) ----
    if (tid < 192) {
      float acc = 0.f;
#pragma unroll 8
      for (int s2 = 0; s2 < 64; ++s2) acc += w_s[s2] * ep_s[s2 * 192 + tid];
      gi_s[tid] = acc + gval;
    }
    __syncthreads();

    // ---- X5: GRU gates + hidden update + publish h-slice ----
    if (tid < 64) {
      float rr = fast_sigmoid(gi_s[tid] + gh_s[tid]);
      float zz = fast_sigmoid(gi_s[64 + tid] + gh_s[64 + tid]);
      float nn = fast_tanh(gi_s[128 + tid] + rr * gh_s[128 + tid]);
      float hp = h_loc[tid];
      float hn = (1.f - zz) * nn + zz * hp;
      h_loc[tid] = hn;
      bf16 hb = (bf16)hn;
      const int j = p * 64 + tid;
      histb[(long)(b * 64 + t) * 512 + j] = hb;   // ordinary: next kernel
      if (t == 63) outhT[b * 512 + j] = hn;
      float hn1 = __shfl_xor(hn, 1);
      if ((tid & 1) == 0) {
        union { bf16 h[2]; unsigned u; } cv;
        cv.h[0] = hb; cv.h[1] = (bf16)hn1;
        // u32 index = (p*64 + tid)/2 = p*32 + tid/2 within [b*256, b*256+256)
        __hip_atomic_store(&hx[b * 256 + p * 32 + (tid >> 1)], cv.u,
                           __ATOMIC_RELAXED, __HIP_MEMORY_SCOPE_AGENT);
      }
    }
    if (t < 63) {
      gsync(bar, b, 8u * (++snc));   // syncA: all h-slices published
      // pull full h(t+1): 256 packed u32 -> h_s[512] (bf16-rounded values)
      {
        unsigned u = coh_load_u32(&hx[b * 256 + tid]);
        h_s[2 * tid] = bflo(u);
        h_s[2 * tid + 1] = bfhi(u);
      }
      __syncthreads();
    }
  }
}

// ---------------- in-place log-softmax over V=32000 per row ----------------
__global__ __launch_bounds__(256) void logsm_k(float* __restrict__ C) {
  const long row = blockIdx.x;
  float* x = C + row * 32000L;
  const int tid = threadIdx.x;
  __shared__ float red[4];
  float s = 0.f;
  for (long i = (long)tid * 4; i < 32000; i += 1024) {
    float4 v = *(const float4*)(x + i);
    s += __expf(v.x);
    s += __expf(v.y);
    s += __expf(v.z);
    s += __expf(v.w);
  }
#pragma unroll
  for (int d = 1; d < 64; d <<= 1) s += __shfl_xor(s, d);
  if ((tid & 63) == 0) red[tid >> 6] = s;
  __syncthreads();
  const float lse = __logf(red[0] + red[1] + red[2] + red[3]);
  for (long i = (long)tid * 4; i < 32000; i += 1024) {
    float4 v = *(const float4*)(x + i);
    v.x -= lse; v.y -= lse; v.z -= lse; v.w -= lse;
    *(float4*)(x + i) = v;
  }
}

// ---------------- launcher ----------------
extern "C" void kernel_launch(void* const* d_in, const int* in_sizes, int n_in,
                              void* d_out, int out_size, void* d_ws, size_t ws_size,
                              hipStream_t stream) {
  const float* enc  = (const float*)d_in[0];   // [32,64,512]
  const float* ehid = (const float*)d_in[1];   // [1,32,512]
  const int* tgt    = (const int*)d_in[2];     // [32,64]
  const float* emb  = (const float*)d_in[3];   // [32000,512]
  const float* Wa   = (const float*)d_in[4];   // [512,512]
  const float* ba   = (const float*)d_in[5];   // [512]
  const float* Ua   = (const float*)d_in[6];   // [512,512]
  const float* bu   = (const float*)d_in[7];   // [512]
  const float* Va   = (const float*)d_in[8];   // [1,512]
  // d_in[9] = bv: softmax shift-invariant, unused
  const float* Wih  = (const float*)d_in[10];  // [1536,1024]
  const float* bih  = (const float*)d_in[11];  // [1536]
  const float* Whh  = (const float*)d_in[12];  // [1536,512]
  const float* bhh  = (const float*)d_in[13];  // [1536]
  const float* Wout = (const float*)d_in[14];  // [32000,512]
  const float* bout = (const float*)d_in[15];  // [32000]

  char* ws = (char*)d_ws;
  size_t off = 0;
  auto alloc = [&](size_t bytes) {
    void* pp = ws + off;
    off += (bytes + 255) & ~(size_t)255;
    return pp;
  };
  unsigned* bar  = (unsigned*)alloc(32 * 32 * 4);              // per-batch counters
  unsigned* hx   = (unsigned*)alloc((long)32 * 256 * 4);       // packed h exchange
  float* psx     = (float*)alloc((long)32 * 8 * 64 * 4);       // partial scores
  bf16* enc_bf   = (bf16*)alloc((long)2048 * 512 * 2);
  bf16* Wc_bf    = (bf16*)alloc((long)2048 * 512 * 2);         // [Wa;W_hh]
  bf16* Ua_bf    = (bf16*)alloc((long)512 * 512 * 2);
  bf16* Wihx_bf  = (bf16*)alloc((long)1536 * 512 * 2);
  bf16* Wihc_bf  = (bf16*)alloc((long)1536 * 512 * 2);
  bf16* xemb_bf  = (bf16*)alloc((long)2048 * 512 * 2);
  bf16* histb    = (bf16*)alloc((long)2048 * 512 * 2);
  bf16* Wout_bf  = (bf16*)alloc((long)32000 * 512 * 2);
  float* kp      = (float*)alloc((long)2048 * 512 * 4);
  float* kpT     = (float*)alloc((long)32 * 512 * 64 * 4);
  float* gix     = (float*)alloc((long)2048 * 1536 * 4);
  float* ep      = (float*)alloc((long)2048 * 1536 * 4);
  (void)ws_size; (void)in_sizes; (void)n_in; (void)out_size;

  float* out0   = (float*)d_out;              // [32,64,32000] log-probs
  float* outhT  = out0 + (long)2048 * 32000;  // [1,32,512]
  float* outatt = outhT + (long)32 * 512;     // [32,64,64]

  hipMemsetAsync(bar, 0, 32 * 32 * 4, stream);

  dim3 blk(256);
  // conversions / packing
  f2bf_k<<<dim3(1024), blk, 0, stream>>>(enc, enc_bf, (long)2048 * 512);
  f2bf_k<<<dim3(256), blk, 0, stream>>>(Ua, Ua_bf, (long)512 * 512);
  f2bf_k<<<dim3(16000), blk, 0, stream>>>(Wout, Wout_bf, (long)32000 * 512);
  f2bf_k<<<dim3(256), blk, 0, stream>>>(Wa, Wc_bf, (long)512 * 512);
  f2bf_k<<<dim3(768), blk, 0, stream>>>(Whh, Wc_bf + (long)512 * 512, (long)1536 * 512);
  split_wih_k<<<dim3(768), blk, 0, stream>>>(Wih, Wihx_bf, Wihc_bf);
  embed_k<<<dim3(1024), blk, 0, stream>>>(tgt, emb, xemb_bf);

  // step-invariant GEMMs
  gemm_bt<<<dim3(16 * 4), blk, 0, stream>>>(enc_bf, Ua_bf, bu, kp, 512);         // keys_proj
  kpt_k<<<dim3(4096), blk, 0, stream>>>(kp, kpT);
  gemm_bt<<<dim3(16 * 12), blk, 0, stream>>>(xemb_bf, Wihx_bf, bih, gix, 1536);  // gi_x (+b_ih)
  gemm_bt<<<dim3(16 * 12), blk, 0, stream>>>(enc_bf, Wihc_bf, (const float*)nullptr, ep, 1536);

  // sequential decode: 32 independent 8-block groups, no global barrier
  recurrence_k<<<dim3(NB_REC), blk, 0, stream>>>(Wc_bf, ba, bhh, ehid, hx, psx, histb,
                                                 kpT, Va, gix, ep, outhT, outatt, bar);

  // logits = h_hist @ Wout^T + bout, then in-place log-softmax
  gemm_bt<<<dim3(16 * 250), blk, 0, stream>>>(histb, Wout_bf, bout, out0, 32000);
  logsm_k<<<dim3(2048), blk, 0, stream>>>(out0);
}